// Round 2
// baseline (930.357 us; speedup 1.0000x reference)
//
#include <hip/hip_runtime.h>

#define L_ 2048
#define H_ 8

typedef __attribute__((ext_vector_type(8))) short short8;
typedef __attribute__((ext_vector_type(4))) float f32x4;

static constexpr size_t OFF_S = 2097152;            // B*L*H*D
static constexpr size_t OFF_P = OFF_S + 67108864;   // + B*H*L*L
static constexpr size_t OFF_G = OFF_P + 67108864;

// ws layout (bytes): K tiles at 1 MB (4 MB), V tiles at 5 MB (4 MB)
static constexpr size_t WS_K = 1u << 20;
static constexpr size_t WS_V = WS_K + (4u << 20);

__device__ __forceinline__ unsigned short f2bf(float x) {
    union { float f; unsigned int u; } c; c.f = x;
    unsigned int u = c.u;
    u += 0x7fffu + ((u >> 16) & 1u);               // RNE
    return (unsigned short)(u >> 16);
}

__device__ __forceinline__ void gld_lds16(const unsigned short* g, unsigned short* l) {
    __builtin_amdgcn_global_load_lds(
        (const __attribute__((address_space(1))) void*)g,
        (__attribute__((address_space(3))) void*)l, 16, 0, 0);
}

// ===== kernel 0: K -> bf16 swizzled tiles; V -> bf16 transposed swizzled tiles =====
// tile image: 64 rows x 64 bf16; element (r, chunk c) at r*64 + (c ^ (r&7))*8 shorts.
__global__ __launch_bounds__(256) void prep(
    const float* __restrict__ k, const float* __restrict__ v,
    unsigned short* __restrict__ wsK, unsigned short* __restrict__ wsV)
{
    const int tid = threadIdx.x;
    const int blk = blockIdx.x;
    __shared__ __attribute__((aligned(16))) unsigned short tr[64][72];
    if (blk < 512) {                                 // K path: (bh, t)
        const int bh = blk >> 5, t = blk & 31;
        const int b = bh >> 3, h = bh & 7;
        unsigned short* dst = wsK + (size_t)(bh * 32 + t) * 4096;
        #pragma unroll
        for (int p = 0; p < 2; ++p) {
            const int cid = tid + (p << 8);
            const int r = cid >> 3, c = cid & 7;
            const int j = (t << 6) + r;
            const float4* src = reinterpret_cast<const float4*>(
                k + (((size_t)((b * L_ + j) * H_ + h)) << 6) + (c << 3));
            float4 x0 = src[0], x1 = src[1];
            union { short8 s; unsigned short u[8]; } w;
            w.u[0]=f2bf(x0.x); w.u[1]=f2bf(x0.y); w.u[2]=f2bf(x0.z); w.u[3]=f2bf(x0.w);
            w.u[4]=f2bf(x1.x); w.u[5]=f2bf(x1.y); w.u[6]=f2bf(x1.z); w.u[7]=f2bf(x1.w);
            *reinterpret_cast<short8*>(dst + r * 64 + ((c ^ (r & 7)) << 3)) = w.s;
        }
    } else {                                         // V path: transpose via LDS
        const int vb = blk - 512;
        const int bh = vb >> 5, t = vb & 31;
        const int b = bh >> 3, h = bh & 7;
        const int col4 = (tid & 15) << 2;
        #pragma unroll
        for (int p = 0; p < 4; ++p) {
            const int r = (tid >> 4) + (p << 4);
            const int j = (t << 6) + r;
            float4 x = *reinterpret_cast<const float4*>(
                v + (((size_t)((b * L_ + j) * H_ + h)) << 6) + col4);
            tr[col4 + 0][r] = f2bf(x.x); tr[col4 + 1][r] = f2bf(x.y);
            tr[col4 + 2][r] = f2bf(x.z); tr[col4 + 3][r] = f2bf(x.w);
        }
        __syncthreads();
        unsigned short* dst = wsV + (size_t)(bh * 32 + t) * 4096;
        #pragma unroll
        for (int p = 0; p < 2; ++p) {
            const int cid = tid + (p << 8);
            const int d = cid >> 3, cj = cid & 7;
            short8 s = *reinterpret_cast<const short8*>(&tr[d][cj << 3]);
            *reinterpret_cast<short8*>(dst + d * 64 + ((cj ^ (d & 7)) << 3)) = s;
        }
    }
}

// ===== kernel 1: fused attention + normalize + prior + sigma_out =====
// Phase 1: LDS-staged QK->exp->PV over lower-triangle tiles (no series store).
// Phase 2: barrier-free re-walk with SWAPPED mfma operands: lane holds P^T
//          (4 consecutive series columns of one row) -> series/prior/sigma
//          all share ONE float4 address per thread per tile.
__global__ __launch_bounds__(256) void fused(
    const float* __restrict__ q, const float* __restrict__ sg,
    const unsigned short* __restrict__ wsK, const unsigned short* __restrict__ wsV,
    float* __restrict__ out)
{
    __shared__ __attribute__((aligned(16))) unsigned short Kb[2][4096];
    __shared__ __attribute__((aligned(16))) unsigned short Vb[2][4096];
    __shared__ __attribute__((aligned(16))) unsigned short Pt[16][72];
    __shared__ float l_sums[16];
    __shared__ float sA[16], sC2[16], sS[16];

    const int tid  = threadIdx.x;
    const int wv   = tid >> 6;
    const int lane = tid & 63;
    const int quad = lane >> 4;
    const int l16  = lane & 15;

    const int blk = blockIdx.x;
    const int s   = 127 - (blk >> 4);                // heavy strips first
    const int bh  = blk & 15;
    const int b   = bh >> 3, h = bh & 7;
    const int i0  = s << 4;

    // sigma-derived per-row params (independent of phase 1 -> compute up front)
    if (tid < 16) {
        l_sums[tid] = 0.0f;
        const int i = i0 + tid;
        const float x = sg[(size_t)((b * L_ + i) * H_ + h)];
        const float sgm = 1.0f / (1.0f + __expf(-5.0f * x)) + 1e-5f;
        const float sp  = expm1f(sgm * 1.0986122886681098f);   // 3^sgm - 1
        sS[tid]  = sp;
        sA[tid]  = 0.3989422804014327f / sp;
        sC2[tid] = 0.5f / (sp * sp);
    }

    // Q A-fragments (fp32 -> bf16, once per block)
    short8 a0, a1;
    {
        const float* qr = q + (((size_t)((b * L_ + (i0 + l16)) * H_ + h)) << 6);
        const float4* q4 = reinterpret_cast<const float4*>(qr) + quad * 2;
        float4 x0 = q4[0], x1 = q4[1];
        float4 y0 = q4[8], y1 = q4[9];
        union { short8 v8; unsigned short u[8]; } fa, fb;
        fa.u[0]=f2bf(x0.x); fa.u[1]=f2bf(x0.y); fa.u[2]=f2bf(x0.z); fa.u[3]=f2bf(x0.w);
        fa.u[4]=f2bf(x1.x); fa.u[5]=f2bf(x1.y); fa.u[6]=f2bf(x1.z); fa.u[7]=f2bf(x1.w);
        fb.u[0]=f2bf(y0.x); fb.u[1]=f2bf(y0.y); fb.u[2]=f2bf(y0.z); fb.u[3]=f2bf(y0.w);
        fb.u[4]=f2bf(y1.x); fb.u[5]=f2bf(y1.y); fb.u[6]=f2bf(y1.z); fb.u[7]=f2bf(y1.w);
        a0 = fa.v8; a1 = fb.v8;
    }

    const int ntiles = (s >> 2) + 1;
    const unsigned short* gK = wsK + ((size_t)bh * 32) * 4096;
    const unsigned short* gV = wsV + ((size_t)bh * 32) * 4096;

    #define STAGE(buf, t) do {                                              \
        const unsigned short* _sk = gK + (size_t)(t) * 4096;                \
        const unsigned short* _sv = gV + (size_t)(t) * 4096;                \
        _Pragma("unroll")                                                   \
        for (int _qq = 0; _qq < 2; ++_qq) {                                 \
            const int _off = (wv << 10) + (_qq << 9);                       \
            gld_lds16(_sk + _off + (lane << 3), &Kb[buf][_off]);            \
            gld_lds16(_sv + _off + (lane << 3), &Vb[buf][_off]);            \
        }                                                                   \
    } while (0)

    f32x4 oacc = {0.f, 0.f, 0.f, 0.f};
    float lpart[4] = {0.f, 0.f, 0.f, 0.f};
    const int r = (wv << 4) + l16;                   // K/V tile row this lane fragments

    STAGE(0, 0);
    for (int t = 0; t < ntiles; ++t) {
        const int p = t & 1;
        __syncthreads();                             // buf[p] staged; prev iter fully done
        if (t + 1 < ntiles) STAGE(1 - p, t + 1);     // overlap next DMA with compute
        short8 b0 = *reinterpret_cast<const short8*>(&Kb[p][r * 64 + ((quad ^ (r & 7)) << 3)]);
        short8 b1 = *reinterpret_cast<const short8*>(&Kb[p][r * 64 + (((quad + 4) ^ (r & 7)) << 3)]);
        f32x4 c4 = {0.f, 0.f, 0.f, 0.f};
        c4 = __builtin_amdgcn_mfma_f32_16x16x32_bf16(a0, b0, c4, 0, 0, 0);
        c4 = __builtin_amdgcn_mfma_f32_16x16x32_bf16(a1, b1, c4, 0, 0, 0);
        const int j = (t << 6) + r;
        #pragma unroll
        for (int rr = 0; rr < 4; ++rr) {
            const int i = i0 + (quad << 2) + rr;
            float pv = (j <= i) ? __expf(c4[rr] * 0.125f - 8.0f) : 0.0f;
            lpart[rr] += pv;
            Pt[(quad << 2) + rr][r] = f2bf(pv);      // C-layout -> A-layout via LDS
        }
        __syncthreads();
        short8 pa0 = *reinterpret_cast<const short8*>(&Pt[l16][quad << 3]);
        short8 pa1 = *reinterpret_cast<const short8*>(&Pt[l16][32 + (quad << 3)]);
        short8 vb0 = *reinterpret_cast<const short8*>(&Vb[p][r * 64 + ((quad ^ (r & 7)) << 3)]);
        short8 vb1 = *reinterpret_cast<const short8*>(&Vb[p][r * 64 + (((quad + 4) ^ (r & 7)) << 3)]);
        oacc = __builtin_amdgcn_mfma_f32_16x16x32_bf16(pa0, vb0, oacc, 0, 0, 0);
        oacc = __builtin_amdgcn_mfma_f32_16x16x32_bf16(pa1, vb1, oacc, 0, 0, 0);
    }
    #undef STAGE

    #pragma unroll
    for (int rr = 0; rr < 4; ++rr) {
        float x = lpart[rr];
        x += __shfl_xor(x, 1); x += __shfl_xor(x, 2);
        x += __shfl_xor(x, 4); x += __shfl_xor(x, 8);
        if (l16 == 0) atomicAdd(&l_sums[(quad << 2) + rr], x);
    }
    __syncthreads();                                 // l_sums final; params visible

    {
        float inv[4];
        #pragma unroll
        for (int rr = 0; rr < 4; ++rr) inv[rr] = 1.0f / l_sums[(quad << 2) + rr];
        #pragma unroll
        for (int rr = 0; rr < 4; ++rr) {
            const int i = i0 + (quad << 2) + rr;
            out[(((size_t)((b * L_ + i) * H_ + h)) << 6) + (wv << 4) + l16] = oacc[rr] * inv[rr];
        }
    }

    // ===== phase 2: barrier-free streaming writeback (swapped-operand QK) =====
    // lane (wv,quad,l16) owns row i = i0+l16, columns cb..cb+3,
    // cb = t*64 + wv*16 + quad*4  -> one shared float4 address for all 3 streams.
    float* outS = out + OFF_S;
    float* outP = out + OFF_P;
    float* outG = out + OFF_G;

    const float invi = 1.0f / l_sums[l16];
    const float Arow = sA[l16], C2r = sC2[l16], Srow = sS[l16];
    const int   ilim = i0 + l16;
    const float fi   = (float)ilim;
    const size_t base = ((size_t)(bh * L_ + ilim)) << 11;
    const int cb0 = (wv << 4) + (quad << 2);
    const float4 sv = {Srow, Srow, Srow, Srow};

    // per-thread K fragment offsets inside a tile (shorts) — same r as phase 1
    const int off0 = r * 64 + ((quad ^ (r & 7)) << 3);
    const int off1 = r * 64 + (((quad + 4) ^ (r & 7)) << 3);

    short8 kb0 = *reinterpret_cast<const short8*>(gK + off0);
    short8 kb1 = *reinterpret_cast<const short8*>(gK + off1);
    int t = 0;
    for (; t < ntiles; ++t) {
        short8 kn0 = kb0, kn1 = kb1;
        if (t + 1 < ntiles) {                        // reg prefetch: next tile's frags
            const unsigned short* kp = gK + (((size_t)(t + 1)) << 12);
            kn0 = *reinterpret_cast<const short8*>(kp + off0);
            kn1 = *reinterpret_cast<const short8*>(kp + off1);
        }
        // swapped operands: c4[rr] = P[j = t*64 + wv*16 + quad*4 + rr][i = i0+l16]
        f32x4 c4 = {0.f, 0.f, 0.f, 0.f};
        c4 = __builtin_amdgcn_mfma_f32_16x16x32_bf16(kb0, a0, c4, 0, 0, 0);
        c4 = __builtin_amdgcn_mfma_f32_16x16x32_bf16(kb1, a1, c4, 0, 0, 0);
        const int cb = (t << 6) + cb0;
        float4 se;
        se.x = (cb + 0 <= ilim) ? __expf(c4[0] * 0.125f - 8.0f) * invi : 0.0f;
        se.y = (cb + 1 <= ilim) ? __expf(c4[1] * 0.125f - 8.0f) * invi : 0.0f;
        se.z = (cb + 2 <= ilim) ? __expf(c4[2] * 0.125f - 8.0f) * invi : 0.0f;
        se.w = (cb + 3 <= ilim) ? __expf(c4[3] * 0.125f - 8.0f) * invi : 0.0f;
        const float d0 = fi - (float)cb;
        const float d1 = d0 - 1.f, d2 = d0 - 2.f, d3 = d0 - 3.f;
        float4 pr;
        pr.x = Arow * __expf(-d0 * d0 * C2r);
        pr.y = Arow * __expf(-d1 * d1 * C2r);
        pr.z = Arow * __expf(-d2 * d2 * C2r);
        pr.w = Arow * __expf(-d3 * d3 * C2r);
        *reinterpret_cast<float4*>(outS + base + cb) = se;
        *reinterpret_cast<float4*>(outP + base + cb) = pr;
        *reinterpret_cast<float4*>(outG + base + cb) = sv;
        kb0 = kn0; kb1 = kn1;
    }
    const float4 z4 = {0.f, 0.f, 0.f, 0.f};
    for (; t < 32; ++t) {                            // pure streaming: zeros + prior + sigma
        const int cb = (t << 6) + cb0;
        const float d0 = fi - (float)cb;
        const float d1 = d0 - 1.f, d2 = d0 - 2.f, d3 = d0 - 3.f;
        float4 pr;
        pr.x = Arow * __expf(-d0 * d0 * C2r);
        pr.y = Arow * __expf(-d1 * d1 * C2r);
        pr.z = Arow * __expf(-d2 * d2 * C2r);
        pr.w = Arow * __expf(-d3 * d3 * C2r);
        *reinterpret_cast<float4*>(outS + base + cb) = z4;
        *reinterpret_cast<float4*>(outP + base + cb) = pr;
        *reinterpret_cast<float4*>(outG + base + cb) = sv;
    }
}

extern "C" void kernel_launch(void* const* d_in, const int* in_sizes, int n_in,
                              void* d_out, int out_size, void* d_ws, size_t ws_size,
                              hipStream_t stream) {
    const float* q  = (const float*)d_in[0];
    const float* k  = (const float*)d_in[1];
    const float* v  = (const float*)d_in[2];
    const float* sg = (const float*)d_in[3];
    float* outp = (float*)d_out;
    unsigned short* wsK = (unsigned short*)((char*)d_ws + WS_K);
    unsigned short* wsV = (unsigned short*)((char*)d_ws + WS_V);
    prep<<<dim3(1024), dim3(256), 0, stream>>>(k, v, wsK, wsV);
    fused<<<dim3(2048), dim3(256), 0, stream>>>(q, sg, wsK, wsV, outp);
}

// Round 4
// 874.506 us; speedup vs baseline: 1.0639x; 1.0639x over previous
//
#include <hip/hip_runtime.h>

#define L_ 2048
#define H_ 8

typedef __attribute__((ext_vector_type(8))) short short8;
typedef __attribute__((ext_vector_type(4))) float f32x4;

static constexpr size_t OFF_S = 2097152;            // B*L*H*D
static constexpr size_t OFF_P = OFF_S + 67108864;   // + B*H*L*L
static constexpr size_t OFF_G = OFF_P + 67108864;

// ws layout (bytes): K tiles at 1 MB (4 MB), V tiles at 5 MB (4 MB)
static constexpr size_t WS_K = 1u << 20;
static constexpr size_t WS_V = WS_K + (4u << 20);

__device__ __forceinline__ unsigned short f2bf(float x) {
    union { float f; unsigned int u; } c; c.f = x;
    unsigned int u = c.u;
    u += 0x7fffu + ((u >> 16) & 1u);               // RNE
    return (unsigned short)(u >> 16);
}

__device__ __forceinline__ void gld_lds16(const unsigned short* g, unsigned short* l) {
    __builtin_amdgcn_global_load_lds(
        (const __attribute__((address_space(1))) void*)g,
        (__attribute__((address_space(3))) void*)l, 16, 0, 0);
}

// non-temporal stores: keep the 768 MB output stream out of L2/L3 so the
// bf16 K/V workspace stays cache-resident for concurrently-running phase 1.
// NOTE: builtin requires native clang vector types, not HIP_vector_type.
__device__ __forceinline__ void st_nt4(float* p, f32x4 v) {
    __builtin_nontemporal_store(v, reinterpret_cast<f32x4*>(p));
}
__device__ __forceinline__ void st_nt1(float* p, float v) {
    __builtin_nontemporal_store(v, p);
}

// ===== kernel 0: K -> bf16 swizzled tiles; V -> bf16 transposed swizzled tiles =====
// tile image: 64 rows x 64 bf16; element (r, chunk c) at r*64 + (c ^ (r&7))*8 shorts.
__global__ __launch_bounds__(256) void prep(
    const float* __restrict__ k, const float* __restrict__ v,
    unsigned short* __restrict__ wsK, unsigned short* __restrict__ wsV)
{
    const int tid = threadIdx.x;
    const int blk = blockIdx.x;
    __shared__ __attribute__((aligned(16))) unsigned short tr[64][72];
    if (blk < 512) {                                 // K path: (bh, t)
        const int bh = blk >> 5, t = blk & 31;
        const int b = bh >> 3, h = bh & 7;
        unsigned short* dst = wsK + (size_t)(bh * 32 + t) * 4096;
        #pragma unroll
        for (int p = 0; p < 2; ++p) {
            const int cid = tid + (p << 8);
            const int r = cid >> 3, c = cid & 7;
            const int j = (t << 6) + r;
            const float4* src = reinterpret_cast<const float4*>(
                k + (((size_t)((b * L_ + j) * H_ + h)) << 6) + (c << 3));
            float4 x0 = src[0], x1 = src[1];
            union { short8 s; unsigned short u[8]; } w;
            w.u[0]=f2bf(x0.x); w.u[1]=f2bf(x0.y); w.u[2]=f2bf(x0.z); w.u[3]=f2bf(x0.w);
            w.u[4]=f2bf(x1.x); w.u[5]=f2bf(x1.y); w.u[6]=f2bf(x1.z); w.u[7]=f2bf(x1.w);
            *reinterpret_cast<short8*>(dst + r * 64 + ((c ^ (r & 7)) << 3)) = w.s;
        }
    } else {                                         // V path: transpose via LDS
        const int vb = blk - 512;
        const int bh = vb >> 5, t = vb & 31;
        const int b = bh >> 3, h = bh & 7;
        const int col4 = (tid & 15) << 2;
        #pragma unroll
        for (int p = 0; p < 4; ++p) {
            const int r = (tid >> 4) + (p << 4);
            const int j = (t << 6) + r;
            float4 x = *reinterpret_cast<const float4*>(
                v + (((size_t)((b * L_ + j) * H_ + h)) << 6) + col4);
            tr[col4 + 0][r] = f2bf(x.x); tr[col4 + 1][r] = f2bf(x.y);
            tr[col4 + 2][r] = f2bf(x.z); tr[col4 + 3][r] = f2bf(x.w);
        }
        __syncthreads();
        unsigned short* dst = wsV + (size_t)(bh * 32 + t) * 4096;
        #pragma unroll
        for (int p = 0; p < 2; ++p) {
            const int cid = tid + (p << 8);
            const int d = cid >> 3, cj = cid & 7;
            short8 s = *reinterpret_cast<const short8*>(&tr[d][cj << 3]);
            *reinterpret_cast<short8*>(dst + d * 64 + ((cj ^ (d & 7)) << 3)) = s;
        }
    }
}

// ===== kernel 1: fused attention + normalize + prior + sigma_out =====
// Phase 1: LDS-staged QK->exp->PV over lower-triangle tiles (no series store).
// Phase 2: barrier-free re-walk (r1 layout): K frags reloaded from cache-hot ws
//          to regs, QK recomputed, normalized series + prior + sigma streamed
//          with NON-TEMPORAL stores.
__global__ __launch_bounds__(256) void fused(
    const float* __restrict__ q, const float* __restrict__ sg,
    const unsigned short* __restrict__ wsK, const unsigned short* __restrict__ wsV,
    float* __restrict__ out)
{
    __shared__ __attribute__((aligned(16))) unsigned short Kb[2][4096];
    __shared__ __attribute__((aligned(16))) unsigned short Vb[2][4096];
    __shared__ __attribute__((aligned(16))) unsigned short Pt[16][72];
    __shared__ float l_sums[16];
    __shared__ float sA[16], sC2[16], sS[16];

    const int tid  = threadIdx.x;
    const int wv   = tid >> 6;
    const int lane = tid & 63;
    const int quad = lane >> 4;
    const int l16  = lane & 15;

    const int blk = blockIdx.x;
    const int s   = 127 - (blk >> 4);                // heavy strips first
    const int bh  = blk & 15;
    const int b   = bh >> 3, h = bh & 7;
    const int i0  = s << 4;

    const int ntiles = (s >> 2) + 1;
    const unsigned short* gK = wsK + ((size_t)bh * 32) * 4096;
    const unsigned short* gV = wsV + ((size_t)bh * 32) * 4096;

    #define STAGE(buf, t) do {                                              \
        const unsigned short* _sk = gK + (size_t)(t) * 4096;                \
        const unsigned short* _sv = gV + (size_t)(t) * 4096;                \
        _Pragma("unroll")                                                   \
        for (int _qq = 0; _qq < 2; ++_qq) {                                 \
            const int _off = (wv << 10) + (_qq << 9);                       \
            gld_lds16(_sk + _off + (lane << 3), &Kb[buf][_off]);            \
            gld_lds16(_sv + _off + (lane << 3), &Vb[buf][_off]);            \
        }                                                                   \
    } while (0)

    STAGE(0, 0);                                     // issue first DMA ASAP

    // sigma-derived per-row params (independent of phase 1 -> compute up front)
    if (tid < 16) {
        l_sums[tid] = 0.0f;
        const int i = i0 + tid;
        const float x = sg[(size_t)((b * L_ + i) * H_ + h)];
        const float sgm = 1.0f / (1.0f + __expf(-5.0f * x)) + 1e-5f;
        const float sp  = expm1f(sgm * 1.0986122886681098f);   // 3^sgm - 1
        sS[tid]  = sp;
        sA[tid]  = 0.3989422804014327f / sp;
        sC2[tid] = 0.5f / (sp * sp);
    }

    // Q A-fragments (fp32 -> bf16, once per block) — overlaps first DMA
    short8 a0, a1;
    {
        const float* qr = q + (((size_t)((b * L_ + (i0 + l16)) * H_ + h)) << 6);
        const float4* q4 = reinterpret_cast<const float4*>(qr) + quad * 2;
        float4 x0 = q4[0], x1 = q4[1];
        float4 y0 = q4[8], y1 = q4[9];
        union { short8 v8; unsigned short u[8]; } fa, fb;
        fa.u[0]=f2bf(x0.x); fa.u[1]=f2bf(x0.y); fa.u[2]=f2bf(x0.z); fa.u[3]=f2bf(x0.w);
        fa.u[4]=f2bf(x1.x); fa.u[5]=f2bf(x1.y); fa.u[6]=f2bf(x1.z); fa.u[7]=f2bf(x1.w);
        fb.u[0]=f2bf(y0.x); fb.u[1]=f2bf(y0.y); fb.u[2]=f2bf(y0.z); fb.u[3]=f2bf(y0.w);
        fb.u[4]=f2bf(y1.x); fb.u[5]=f2bf(y1.y); fb.u[6]=f2bf(y1.z); fb.u[7]=f2bf(y1.w);
        a0 = fa.v8; a1 = fb.v8;
    }

    f32x4 oacc = {0.f, 0.f, 0.f, 0.f};
    float lpart[4] = {0.f, 0.f, 0.f, 0.f};
    const int r = (wv << 4) + l16;                   // K/V tile row this lane fragments

    for (int t = 0; t < ntiles; ++t) {
        const int p = t & 1;
        __syncthreads();                             // buf[p] staged; prev iter fully done
        if (t + 1 < ntiles) STAGE(1 - p, t + 1);     // overlap next DMA with compute
        short8 b0 = *reinterpret_cast<const short8*>(&Kb[p][r * 64 + ((quad ^ (r & 7)) << 3)]);
        short8 b1 = *reinterpret_cast<const short8*>(&Kb[p][r * 64 + (((quad + 4) ^ (r & 7)) << 3)]);
        f32x4 c4 = {0.f, 0.f, 0.f, 0.f};
        c4 = __builtin_amdgcn_mfma_f32_16x16x32_bf16(a0, b0, c4, 0, 0, 0);
        c4 = __builtin_amdgcn_mfma_f32_16x16x32_bf16(a1, b1, c4, 0, 0, 0);
        const int j = (t << 6) + r;
        #pragma unroll
        for (int rr = 0; rr < 4; ++rr) {
            const int i = i0 + (quad << 2) + rr;
            float pv = (j <= i) ? __expf(c4[rr] * 0.125f - 8.0f) : 0.0f;
            lpart[rr] += pv;
            Pt[(quad << 2) + rr][r] = f2bf(pv);      // C-layout -> A-layout via LDS
        }
        __syncthreads();
        short8 pa0 = *reinterpret_cast<const short8*>(&Pt[l16][quad << 3]);
        short8 pa1 = *reinterpret_cast<const short8*>(&Pt[l16][32 + (quad << 3)]);
        short8 vb0 = *reinterpret_cast<const short8*>(&Vb[p][r * 64 + ((quad ^ (r & 7)) << 3)]);
        short8 vb1 = *reinterpret_cast<const short8*>(&Vb[p][r * 64 + (((quad + 4) ^ (r & 7)) << 3)]);
        oacc = __builtin_amdgcn_mfma_f32_16x16x32_bf16(pa0, vb0, oacc, 0, 0, 0);
        oacc = __builtin_amdgcn_mfma_f32_16x16x32_bf16(pa1, vb1, oacc, 0, 0, 0);
    }
    #undef STAGE

    #pragma unroll
    for (int rr = 0; rr < 4; ++rr) {
        float x = lpart[rr];
        x += __shfl_xor(x, 1); x += __shfl_xor(x, 2);
        x += __shfl_xor(x, 4); x += __shfl_xor(x, 8);
        if (l16 == 0) atomicAdd(&l_sums[(quad << 2) + rr], x);
    }
    __syncthreads();                                 // l_sums final; params visible

    float inv[4];
    #pragma unroll
    for (int rr = 0; rr < 4; ++rr) inv[rr] = 1.0f / l_sums[(quad << 2) + rr];
    #pragma unroll
    for (int rr = 0; rr < 4; ++rr) {
        const int i = i0 + (quad << 2) + rr;
        st_nt1(out + (((size_t)((b * L_ + i) * H_ + h)) << 6) + (wv << 4) + l16,
               oacc[rr] * inv[rr]);
    }

    // ===== phase 2: barrier-free streaming writeback (r1 layout, nt stores) =====
    float* outS = out + OFF_S;
    float* outP = out + OFF_P;
    float* outG = out + OFF_G;

    const int srow = tid >> 4, scol = (tid & 15) << 2;
    const float Arow = sA[srow], C2r = sC2[srow], Srow = sS[srow];
    const size_t rowb = ((size_t)(bh * L_ + i0 + srow)) << 11;
    const float fi = (float)(i0 + srow);
    const f32x4 sv = {Srow, Srow, Srow, Srow};

    // per-thread K fragment offsets inside a tile (shorts) — same r as phase 1
    const int off0 = r * 64 + ((quad ^ (r & 7)) << 3);
    const int off1 = r * 64 + (((quad + 4) ^ (r & 7)) << 3);
    float* psb = outS + (((size_t)(bh * L_ + i0 + (quad << 2))) << 11) + r;

    short8 kb0 = *reinterpret_cast<const short8*>(gK + off0);
    short8 kb1 = *reinterpret_cast<const short8*>(gK + off1);
    int t = 0;
    for (; t < ntiles; ++t) {
        short8 kn0 = kb0, kn1 = kb1;
        if (t + 1 < ntiles) {                        // reg prefetch: next tile's frags
            const unsigned short* kp = gK + (((size_t)(t + 1)) << 12);
            kn0 = *reinterpret_cast<const short8*>(kp + off0);
            kn1 = *reinterpret_cast<const short8*>(kp + off1);
        }
        f32x4 c4 = {0.f, 0.f, 0.f, 0.f};
        c4 = __builtin_amdgcn_mfma_f32_16x16x32_bf16(a0, kb0, c4, 0, 0, 0);
        c4 = __builtin_amdgcn_mfma_f32_16x16x32_bf16(a1, kb1, c4, 0, 0, 0);
        const int j = (t << 6) + r;
        #pragma unroll
        for (int rr = 0; rr < 4; ++rr) {
            const int i = i0 + (quad << 2) + rr;
            const float pv = (j <= i) ? __expf(c4[rr] * 0.125f - 8.0f) * inv[rr] : 0.0f;
            st_nt1(psb + (((size_t)rr << 11) + (t << 6)), pv);
        }
        const int c = (t << 6) + scol;
        const float d0 = fi - (float)c;
        const float d1 = d0 - 1.f, d2 = d0 - 2.f, d3 = d0 - 3.f;
        f32x4 pr;
        pr.x = Arow * __expf(-d0 * d0 * C2r);
        pr.y = Arow * __expf(-d1 * d1 * C2r);
        pr.z = Arow * __expf(-d2 * d2 * C2r);
        pr.w = Arow * __expf(-d3 * d3 * C2r);
        st_nt4(outP + rowb + c, pr);
        st_nt4(outG + rowb + c, sv);
        kb0 = kn0; kb1 = kn1;
    }
    const f32x4 z4 = {0.f, 0.f, 0.f, 0.f};
    for (; t < 32; ++t) {                            // pure streaming: zeros + prior + sigma
        const int c = (t << 6) + scol;
        const float d0 = fi - (float)c;
        const float d1 = d0 - 1.f, d2 = d0 - 2.f, d3 = d0 - 3.f;
        f32x4 pr;
        pr.x = Arow * __expf(-d0 * d0 * C2r);
        pr.y = Arow * __expf(-d1 * d1 * C2r);
        pr.z = Arow * __expf(-d2 * d2 * C2r);
        pr.w = Arow * __expf(-d3 * d3 * C2r);
        st_nt4(outS + rowb + c, z4);
        st_nt4(outP + rowb + c, pr);
        st_nt4(outG + rowb + c, sv);
    }
}

extern "C" void kernel_launch(void* const* d_in, const int* in_sizes, int n_in,
                              void* d_out, int out_size, void* d_ws, size_t ws_size,
                              hipStream_t stream) {
    const float* q  = (const float*)d_in[0];
    const float* k  = (const float*)d_in[1];
    const float* v  = (const float*)d_in[2];
    const float* sg = (const float*)d_in[3];
    float* outp = (float*)d_out;
    unsigned short* wsK = (unsigned short*)((char*)d_ws + WS_K);
    unsigned short* wsV = (unsigned short*)((char*)d_ws + WS_V);
    prep<<<dim3(1024), dim3(256), 0, stream>>>(k, v, wsK, wsV);
    fused<<<dim3(2048), dim3(256), 0, stream>>>(q, sg, wsK, wsV, outp);
}

// Round 5
// 851.698 us; speedup vs baseline: 1.0924x; 1.0268x over previous
//
#include <hip/hip_runtime.h>

#define L_ 2048
#define H_ 8

typedef __attribute__((ext_vector_type(8))) short short8;
typedef __attribute__((ext_vector_type(4))) float f32x4;

static constexpr size_t OFF_S = 2097152;            // B*L*H*D
static constexpr size_t OFF_P = OFF_S + 67108864;   // + B*H*L*L
static constexpr size_t OFF_G = OFF_P + 67108864;

// ws layout (bytes): K tiles at 1 MB (4 MB), V tiles at 5 MB (4 MB)
static constexpr size_t WS_K = 1u << 20;
static constexpr size_t WS_V = WS_K + (4u << 20);

__device__ __forceinline__ unsigned short f2bf(float x) {
    union { float f; unsigned int u; } c; c.f = x;
    unsigned int u = c.u;
    u += 0x7fffu + ((u >> 16) & 1u);               // RNE
    return (unsigned short)(u >> 16);
}

__device__ __forceinline__ void gld_lds16(const unsigned short* g, unsigned short* l) {
    __builtin_amdgcn_global_load_lds(
        (const __attribute__((address_space(1))) void*)g,
        (__attribute__((address_space(3))) void*)l, 16, 0, 0);
}

// non-temporal stores (native clang vector types required by the builtin)
__device__ __forceinline__ void st_nt4(float* p, f32x4 v) {
    __builtin_nontemporal_store(v, reinterpret_cast<f32x4*>(p));
}
__device__ __forceinline__ void st_nt1(float* p, float v) {
    __builtin_nontemporal_store(v, p);
}

// ===== kernel 0: K -> bf16 swizzled tiles; V -> bf16 transposed swizzled tiles =====
// tile image: 64 rows x 64 bf16; element (r, chunk c) at r*64 + (c ^ (r&7))*8 shorts.
__global__ __launch_bounds__(256) void prep(
    const float* __restrict__ k, const float* __restrict__ v,
    unsigned short* __restrict__ wsK, unsigned short* __restrict__ wsV)
{
    const int tid = threadIdx.x;
    const int blk = blockIdx.x;
    __shared__ __attribute__((aligned(16))) unsigned short tr[64][72];
    if (blk < 512) {                                 // K path: (bh, t)
        const int bh = blk >> 5, t = blk & 31;
        const int b = bh >> 3, h = bh & 7;
        unsigned short* dst = wsK + (size_t)(bh * 32 + t) * 4096;
        #pragma unroll
        for (int p = 0; p < 2; ++p) {
            const int cid = tid + (p << 8);
            const int r = cid >> 3, c = cid & 7;
            const int j = (t << 6) + r;
            const float4* src = reinterpret_cast<const float4*>(
                k + (((size_t)((b * L_ + j) * H_ + h)) << 6) + (c << 3));
            float4 x0 = src[0], x1 = src[1];
            union { short8 s; unsigned short u[8]; } w;
            w.u[0]=f2bf(x0.x); w.u[1]=f2bf(x0.y); w.u[2]=f2bf(x0.z); w.u[3]=f2bf(x0.w);
            w.u[4]=f2bf(x1.x); w.u[5]=f2bf(x1.y); w.u[6]=f2bf(x1.z); w.u[7]=f2bf(x1.w);
            *reinterpret_cast<short8*>(dst + r * 64 + ((c ^ (r & 7)) << 3)) = w.s;
        }
    } else {                                         // V path: transpose via LDS
        const int vb = blk - 512;
        const int bh = vb >> 5, t = vb & 31;
        const int b = bh >> 3, h = bh & 7;
        const int col4 = (tid & 15) << 2;
        #pragma unroll
        for (int p = 0; p < 4; ++p) {
            const int r = (tid >> 4) + (p << 4);
            const int j = (t << 6) + r;
            float4 x = *reinterpret_cast<const float4*>(
                v + (((size_t)((b * L_ + j) * H_ + h)) << 6) + col4);
            tr[col4 + 0][r] = f2bf(x.x); tr[col4 + 1][r] = f2bf(x.y);
            tr[col4 + 2][r] = f2bf(x.z); tr[col4 + 3][r] = f2bf(x.w);
        }
        __syncthreads();
        unsigned short* dst = wsV + (size_t)(bh * 32 + t) * 4096;
        #pragma unroll
        for (int p = 0; p < 2; ++p) {
            const int cid = tid + (p << 8);
            const int d = cid >> 3, cj = cid & 7;
            short8 s = *reinterpret_cast<const short8*>(&tr[d][cj << 3]);
            *reinterpret_cast<short8*>(dst + d * 64 + ((cj ^ (d & 7)) << 3)) = s;
        }
    }
}

// ===== kernel 1: fused attention + normalize + prior + sigma_out =====
// Phase 1: LDS-staged QK->exp->PV over lower-triangle tiles (no series store).
// Phase 2: re-walk with MFMA recompute; normalized P bounced through an f32 LDS
//          tile so every store instruction writes 4 rows x 256 B contiguous
//          (full L2 lines) for series, prior, and sigma. Raw s_barrier + lgkm
//          fences only (no vmcnt drain inside the store loop).
__global__ __launch_bounds__(256) void fused(
    const float* __restrict__ q, const float* __restrict__ sg,
    const unsigned short* __restrict__ wsK, const unsigned short* __restrict__ wsV,
    float* __restrict__ out)
{
    __shared__ __attribute__((aligned(16))) unsigned short Kb[2][4096];
    __shared__ __attribute__((aligned(16))) unsigned short Vb[2][4096];
    __shared__ __attribute__((aligned(16))) unsigned short Pt[16][72];
    __shared__ float l_sums[16];
    __shared__ float sA[16], sC2[16], sS[16];

    const int tid  = threadIdx.x;
    const int wv   = tid >> 6;
    const int lane = tid & 63;
    const int quad = lane >> 4;
    const int l16  = lane & 15;

    const int blk = blockIdx.x;
    const int s   = 127 - (blk >> 4);                // heavy strips first
    const int bh  = blk & 15;
    const int b   = bh >> 3, h = bh & 7;
    const int i0  = s << 4;

    const int ntiles = (s >> 2) + 1;
    const unsigned short* gK = wsK + ((size_t)bh * 32) * 4096;
    const unsigned short* gV = wsV + ((size_t)bh * 32) * 4096;

    #define STAGE(buf, t) do {                                              \
        const unsigned short* _sk = gK + (size_t)(t) * 4096;                \
        const unsigned short* _sv = gV + (size_t)(t) * 4096;                \
        _Pragma("unroll")                                                   \
        for (int _qq = 0; _qq < 2; ++_qq) {                                 \
            const int _off = (wv << 10) + (_qq << 9);                       \
            gld_lds16(_sk + _off + (lane << 3), &Kb[buf][_off]);            \
            gld_lds16(_sv + _off + (lane << 3), &Vb[buf][_off]);            \
        }                                                                   \
    } while (0)

    STAGE(0, 0);                                     // issue first DMA ASAP

    // sigma-derived per-row params (independent of phase 1 -> compute up front)
    if (tid < 16) {
        l_sums[tid] = 0.0f;
        const int i = i0 + tid;
        const float x = sg[(size_t)((b * L_ + i) * H_ + h)];
        const float sgm = 1.0f / (1.0f + __expf(-5.0f * x)) + 1e-5f;
        const float sp  = expm1f(sgm * 1.0986122886681098f);   // 3^sgm - 1
        sS[tid]  = sp;
        sA[tid]  = 0.3989422804014327f / sp;
        sC2[tid] = 0.5f / (sp * sp);
    }

    // Q A-fragments (fp32 -> bf16, once per block) — overlaps first DMA
    short8 a0, a1;
    {
        const float* qr = q + (((size_t)((b * L_ + (i0 + l16)) * H_ + h)) << 6);
        const float4* q4 = reinterpret_cast<const float4*>(qr) + quad * 2;
        float4 x0 = q4[0], x1 = q4[1];
        float4 y0 = q4[8], y1 = q4[9];
        union { short8 v8; unsigned short u[8]; } fa, fb;
        fa.u[0]=f2bf(x0.x); fa.u[1]=f2bf(x0.y); fa.u[2]=f2bf(x0.z); fa.u[3]=f2bf(x0.w);
        fa.u[4]=f2bf(x1.x); fa.u[5]=f2bf(x1.y); fa.u[6]=f2bf(x1.z); fa.u[7]=f2bf(x1.w);
        fb.u[0]=f2bf(y0.x); fb.u[1]=f2bf(y0.y); fb.u[2]=f2bf(y0.z); fb.u[3]=f2bf(y0.w);
        fb.u[4]=f2bf(y1.x); fb.u[5]=f2bf(y1.y); fb.u[6]=f2bf(y1.z); fb.u[7]=f2bf(y1.w);
        a0 = fa.v8; a1 = fb.v8;
    }

    f32x4 oacc = {0.f, 0.f, 0.f, 0.f};
    float lpart[4] = {0.f, 0.f, 0.f, 0.f};
    const int r = (wv << 4) + l16;                   // K/V tile row this lane fragments

    for (int t = 0; t < ntiles; ++t) {
        const int p = t & 1;
        __syncthreads();                             // buf[p] staged; prev iter fully done
        if (t + 1 < ntiles) STAGE(1 - p, t + 1);     // overlap next DMA with compute
        short8 b0 = *reinterpret_cast<const short8*>(&Kb[p][r * 64 + ((quad ^ (r & 7)) << 3)]);
        short8 b1 = *reinterpret_cast<const short8*>(&Kb[p][r * 64 + (((quad + 4) ^ (r & 7)) << 3)]);
        f32x4 c4 = {0.f, 0.f, 0.f, 0.f};
        c4 = __builtin_amdgcn_mfma_f32_16x16x32_bf16(a0, b0, c4, 0, 0, 0);
        c4 = __builtin_amdgcn_mfma_f32_16x16x32_bf16(a1, b1, c4, 0, 0, 0);
        const int j = (t << 6) + r;
        #pragma unroll
        for (int rr = 0; rr < 4; ++rr) {
            const int i = i0 + (quad << 2) + rr;
            float pv = (j <= i) ? __expf(c4[rr] * 0.125f - 8.0f) : 0.0f;
            lpart[rr] += pv;
            Pt[(quad << 2) + rr][r] = f2bf(pv);      // C-layout -> A-layout via LDS
        }
        __syncthreads();
        short8 pa0 = *reinterpret_cast<const short8*>(&Pt[l16][quad << 3]);
        short8 pa1 = *reinterpret_cast<const short8*>(&Pt[l16][32 + (quad << 3)]);
        short8 vb0 = *reinterpret_cast<const short8*>(&Vb[p][r * 64 + ((quad ^ (r & 7)) << 3)]);
        short8 vb1 = *reinterpret_cast<const short8*>(&Vb[p][r * 64 + (((quad + 4) ^ (r & 7)) << 3)]);
        oacc = __builtin_amdgcn_mfma_f32_16x16x32_bf16(pa0, vb0, oacc, 0, 0, 0);
        oacc = __builtin_amdgcn_mfma_f32_16x16x32_bf16(pa1, vb1, oacc, 0, 0, 0);
    }
    #undef STAGE

    #pragma unroll
    for (int rr = 0; rr < 4; ++rr) {
        float x = lpart[rr];
        x += __shfl_xor(x, 1); x += __shfl_xor(x, 2);
        x += __shfl_xor(x, 4); x += __shfl_xor(x, 8);
        if (l16 == 0) atomicAdd(&l_sums[(quad << 2) + rr], x);
    }
    __syncthreads();                                 // l_sums final; params visible

    float inv[4];
    #pragma unroll
    for (int rr = 0; rr < 4; ++rr) inv[rr] = 1.0f / l_sums[(quad << 2) + rr];
    #pragma unroll
    for (int rr = 0; rr < 4; ++rr) {
        const int i = i0 + (quad << 2) + rr;
        st_nt1(out + (((size_t)((b * L_ + i) * H_ + h)) << 6) + (wv << 4) + l16,
               oacc[rr] * inv[rr]);
    }

    // ===== phase 2: streaming writeback, 4 rows x 256 B per store instruction =====
    float* outS = out + OFF_S;
    float* outP = out + OFF_P;
    float* outG = out + OFF_G;
    float* Ps = reinterpret_cast<float*>(&Kb[0][0]); // 16 x 68 f32 bounce tile (4.35 KB)

    // consumer lane map: row = wv*4 + quad (4 rows/wave), col = l16*4
    const int rowc = (wv << 2) + quad;
    const int colc = l16 << 2;
    const float Ac  = sA[rowc], C2c = sC2[rowc], Sc = sS[rowc];
    const float fic = (float)(i0 + rowc);
    const size_t rowbase = ((size_t)(bh * L_ + i0 + rowc)) << 11;
    const f32x4 svc = {Sc, Sc, Sc, Sc};

    // producer K-fragment offsets inside a tile (shorts) — same r as phase 1
    const int off0 = r * 64 + ((quad ^ (r & 7)) << 3);
    const int off1 = r * 64 + (((quad + 4) ^ (r & 7)) << 3);

    short8 kb0 = *reinterpret_cast<const short8*>(gK + off0);
    short8 kb1 = *reinterpret_cast<const short8*>(gK + off1);
    int t = 0;
    for (; t < ntiles; ++t) {
        short8 kn0 = kb0, kn1 = kb1;
        if (t + 1 < ntiles) {                        // reg prefetch: next tile's frags
            const unsigned short* kp = gK + (((size_t)(t + 1)) << 12);
            kn0 = *reinterpret_cast<const short8*>(kp + off0);
            kn1 = *reinterpret_cast<const short8*>(kp + off1);
        }
        f32x4 c4 = {0.f, 0.f, 0.f, 0.f};
        c4 = __builtin_amdgcn_mfma_f32_16x16x32_bf16(a0, kb0, c4, 0, 0, 0);
        c4 = __builtin_amdgcn_mfma_f32_16x16x32_bf16(a1, kb1, c4, 0, 0, 0);
        const int j = (t << 6) + r;
        #pragma unroll
        for (int rr = 0; rr < 4; ++rr) {             // normalized P -> LDS (f32)
            const int i = i0 + (quad << 2) + rr;
            const float pv = (j <= i) ? __expf(c4[rr] * 0.125f - 8.0f) * inv[rr] : 0.0f;
            Ps[((quad << 2) + rr) * 68 + r] = pv;
        }
        asm volatile("s_waitcnt lgkmcnt(0)" ::: "memory");
        __builtin_amdgcn_s_barrier();                // P tile visible to all waves
        asm volatile("" ::: "memory");
        const f32x4 se = *reinterpret_cast<const f32x4*>(&Ps[rowc * 68 + colc]);
        const int c = (t << 6) + colc;
        const float d0 = fic - (float)c;
        const float d1 = d0 - 1.f, d2 = d0 - 2.f, d3 = d0 - 3.f;
        f32x4 pr;
        pr.x = Ac * __expf(-d0 * d0 * C2c);
        pr.y = Ac * __expf(-d1 * d1 * C2c);
        pr.z = Ac * __expf(-d2 * d2 * C2c);
        pr.w = Ac * __expf(-d3 * d3 * C2c);
        st_nt4(outS + rowbase + c, se);
        st_nt4(outP + rowbase + c, pr);
        st_nt4(outG + rowbase + c, svc);
        asm volatile("s_waitcnt lgkmcnt(0)" ::: "memory");
        __builtin_amdgcn_s_barrier();                // WAR: reads done before next writes
        asm volatile("" ::: "memory");
        kb0 = kn0; kb1 = kn1;
    }
    const f32x4 z4 = {0.f, 0.f, 0.f, 0.f};
    for (; t < 32; ++t) {                            // pure streaming: zeros + prior + sigma
        const int c = (t << 6) + colc;
        const float d0 = fic - (float)c;
        const float d1 = d0 - 1.f, d2 = d0 - 2.f, d3 = d0 - 3.f;
        f32x4 pr;
        pr.x = Ac * __expf(-d0 * d0 * C2c);
        pr.y = Ac * __expf(-d1 * d1 * C2c);
        pr.z = Ac * __expf(-d2 * d2 * C2c);
        pr.w = Ac * __expf(-d3 * d3 * C2c);
        st_nt4(outS + rowbase + c, z4);
        st_nt4(outP + rowbase + c, pr);
        st_nt4(outG + rowbase + c, svc);
    }
}

extern "C" void kernel_launch(void* const* d_in, const int* in_sizes, int n_in,
                              void* d_out, int out_size, void* d_ws, size_t ws_size,
                              hipStream_t stream) {
    const float* q  = (const float*)d_in[0];
    const float* k  = (const float*)d_in[1];
    const float* v  = (const float*)d_in[2];
    const float* sg = (const float*)d_in[3];
    float* outp = (float*)d_out;
    unsigned short* wsK = (unsigned short*)((char*)d_ws + WS_K);
    unsigned short* wsV = (unsigned short*)((char*)d_ws + WS_V);
    prep<<<dim3(1024), dim3(256), 0, stream>>>(k, v, wsK, wsV);
    fused<<<dim3(2048), dim3(256), 0, stream>>>(q, sg, wsK, wsV, outp);
}